// Round 9
// baseline (29.141 us; speedup 1.0000x reference)
//
#include <hip/hip_runtime.h>

#define KC 256                   // codebook size
#define NROWS (8*64*64*64/4)     // 524288 rows of dim 4
#define RPT 2                    // rows per thread
#define TPB 256                  // threads per block
#define NB (NROWS/(TPB*RPT))     // 1024 blocks
#define NG (KC/4)                // 64 chunks of 4 centers

// argmax_k (x.c_k - 0.5*||c_k||^2) == argmin_k ||x - c_k||^2.
// Main loop tracks only (best chunk-max, best chunk id): cmp+sel once per
// 4-center chunk. Within-chunk k is recovered in an epilogue that recomputes
// the 4 scores from the SAME mh bits (LDS, single computation site) and the
// same fmaf chain -> bit-identical values -> exact-equality selection.
__global__ __launch_bounds__(TPB) void vq_main(const float* __restrict__ x,
                                               const float* __restrict__ center,
                                               float* __restrict__ out) {
    __shared__ float4 smh4[NG];    // -0.5*||c||^2, packed 4 per float4

    const int tid = threadIdx.x;
    {
        float4 c = reinterpret_cast<const float4*>(center)[tid];
        reinterpret_cast<float*>(smh4)[tid] =
            -0.5f * (c.x * c.x + c.y * c.y + c.z * c.z + c.w * c.w);
    }
    __syncthreads();

    const int base = blockIdx.x * (TPB * RPT) + tid;
    const float4* x4 = reinterpret_cast<const float4*>(x);
    const float4 xa = x4[base];
    const float4 xb = x4[base + TPB];

    float bpa = -__builtin_inff(), bpb = -__builtin_inff();
    int bca = 0, bcb = 0;          // winning chunk ids

#pragma unroll 2
    for (int g = 0; g < NG; ++g) {
        // 16 consecutive codebook floats, uniform index -> s_load_dwordx16.
        float cv[16];
#pragma unroll
        for (int j = 0; j < 16; ++j) cv[j] = center[16 * g + j];
        const float4 m = smh4[g];  // uniform ds_read_b128 broadcast

        float pa0, pa1, pa2, pa3, pb0, pb1, pb2, pb3;
#pragma unroll
        for (int j = 0; j < 4; ++j) {
            const float cx = cv[4*j+0], cy = cv[4*j+1];
            const float cz = cv[4*j+2], cw = cv[4*j+3];
            const float mh = (j == 0) ? m.x : (j == 1) ? m.y : (j == 2) ? m.z : m.w;
            float t = fmaf(xa.x, cx, mh);            // same fma order as all
            t = fmaf(xa.y, cy, t);                   // previous passing rounds
            t = fmaf(xa.z, cz, t);
            t = fmaf(xa.w, cw, t);
            float u = fmaf(xb.x, cx, mh);
            u = fmaf(xb.y, cy, u);
            u = fmaf(xb.z, cz, u);
            u = fmaf(xb.w, cw, u);
            if (j == 0) { pa0 = t; pb0 = u; }
            else if (j == 1) { pa1 = t; pb1 = u; }
            else if (j == 2) { pa2 = t; pb2 = u; }
            else { pa3 = t; pb3 = u; }
        }
        // chunk max: v_max3 + v_max per row
        const float ma = fmaxf(fmaxf(fmaxf(pa0, pa1), pa2), pa3);
        const float mb = fmaxf(fmaxf(fmaxf(pb0, pb1), pb2), pb3);
        // strict '>': earliest chunk wins ties (argmin-first semantics)
        const bool ta = ma > bpa;
        bpa = ta ? ma : bpa;
        bca = ta ? g : bca;        // g <= 63: inline constant
        const bool tb = mb > bpb;
        bpb = tb ? mb : bpb;
        bcb = tb ? g : bcb;
    }

    // Epilogue, once per row. mh comes from smh4 (same bits as main loop);
    // p_j recomputed with the identical fmaf chain -> bit-identical to the
    // main loop's p_j. Select lowest j achieving the locally-computed max.
    auto resolve = [&](const float4 xv, const int bc) -> float4 {
        float cv[16];
#pragma unroll
        for (int j = 0; j < 16; ++j) cv[j] = center[16 * bc + j];  // L1-resident
        const float4 m = smh4[bc];   // divergent LDS read, same bits as main loop
        float p[4];
#pragma unroll
        for (int j = 0; j < 4; ++j) {
            const float cx = cv[4*j+0], cy = cv[4*j+1];
            const float cz = cv[4*j+2], cw = cv[4*j+3];
            const float mh = (j == 0) ? m.x : (j == 1) ? m.y : (j == 2) ? m.z : m.w;
            float t = fmaf(xv.x, cx, mh);
            t = fmaf(xv.y, cy, t);
            t = fmaf(xv.z, cz, t);
            t = fmaf(xv.w, cw, t);
            p[j] = t;
        }
        const float mx = fmaxf(fmaxf(fmaxf(p[0], p[1]), p[2]), p[3]);
        // descending selects: lowest matching j wins
        float wx = cv[12], wy = cv[13], wz = cv[14], ww = cv[15];
        if (p[2] == mx) { wx = cv[8];  wy = cv[9];  wz = cv[10]; ww = cv[11]; }
        if (p[1] == mx) { wx = cv[4];  wy = cv[5];  wz = cv[6];  ww = cv[7];  }
        if (p[0] == mx) { wx = cv[0];  wy = cv[1];  wz = cv[2];  ww = cv[3];  }
        return make_float4(wx, wy, wz, ww);
    };

    reinterpret_cast<float4*>(out)[base]       = resolve(xa, bca);
    reinterpret_cast<float4*>(out)[base + TPB] = resolve(xb, bcb);
}

extern "C" void kernel_launch(void* const* d_in, const int* in_sizes, int n_in,
                              void* d_out, int out_size, void* d_ws, size_t ws_size,
                              hipStream_t stream) {
    const float* x      = (const float*)d_in[0];
    const float* center = (const float*)d_in[1];
    float* out = (float*)d_out;

    vq_main<<<NB, TPB, 0, stream>>>(x, center, out);
}